// Round 15
// baseline (242.907 us; speedup 1.0000x reference)
//
#include <hip/hip_runtime.h>
#include <cstdint>
#include <cstddef>
#include <type_traits>

using f32x4 = __attribute__((ext_vector_type(4))) float;
using s16x8 = __attribute__((ext_vector_type(8))) short;

__device__ __forceinline__ ushort f2bf(float x) {
    uint32_t u = __builtin_bit_cast(uint32_t, x);
    u += 0x7fffu + ((u >> 16) & 1u);          // round-to-nearest-even
    return (ushort)(u >> 16);
}
__device__ __forceinline__ float bflo(uint32_t u) { return __builtin_bit_cast(float, u << 16); }
__device__ __forceinline__ float bfhi(uint32_t u) { return __builtin_bit_cast(float, u & 0xffff0000u); }

__device__ __forceinline__ void dec8(uint4 g, float* x) {
    x[0] = bflo(g.x); x[1] = bfhi(g.x); x[2] = bflo(g.y); x[3] = bfhi(g.y);
    x[4] = bflo(g.z); x[5] = bfhi(g.z); x[6] = bflo(g.w); x[7] = bfhi(g.w);
}

#define GLOAD_LDS16(g, l)                                                                  \
    __builtin_amdgcn_global_load_lds((const __attribute__((address_space(1))) void*)(g),  \
                                     (__attribute__((address_space(3))) void*)(l), 16, 0, 0)

// ---------------------------------------------------------------- CSR build + WT prep (fused)
__global__ __launch_bounds__(256) void degree_ew_wt(const int* __restrict__ ei,
                                                    const float* __restrict__ ew,
                                                    int* __restrict__ deg,
                                                    float* __restrict__ partials,
                                                    int E, int N, int NBE,
                                                    const float* __restrict__ Wl0,
                                                    const float* __restrict__ Wr0,
                                                    ushort* __restrict__ WT0,
                                                    const float* __restrict__ Wl1,
                                                    const float* __restrict__ Wr1,
                                                    ushort* __restrict__ WT1) {
    __shared__ float red[256];
    int bid = blockIdx.x;
    int t = threadIdx.x;
    if (bid < NBE) {
        int e = bid * 256 + t;
        float s = (e < E) ? ew[e] : 0.f;
        red[t] = s; __syncthreads();
        for (int o = 128; o; o >>= 1) { if (t < o) red[t] += red[t + o]; __syncthreads(); }
        if (t == 0) partials[bid] = red[0];
        if (e < E + N) {
            int d = (e < E) ? ei[E + e] : (e - E);
            atomicAdd(&deg[d], 1);
        }
        return;
    }
    int j = (bid - NBE) * 256 + t;
    if (j < 128 * 256) {
        int k = j >> 8, c = j & 255;
        float v = (c < 128) ? Wl0[k * 128 + c] : Wr0[k * 128 + (c - 128)];
        WT0[(size_t)c * 128 + k] = f2bf(v);
        return;
    }
    j -= 128 * 256;
    if (j < 128 * 512) {
        int k = j >> 9, c = j & 511;
        float v = (c < 256) ? Wl1[k * 256 + c] : Wr1[k * 256 + (c - 256)];
        WT1[(size_t)c * 128 + k] = f2bf(v);
    }
}

// multi-block scan, stage 1: per-block (1024 elems) sums + degree-bucket histogram
__global__ void scan_partial(const int* __restrict__ deg, int n, int* __restrict__ bsum,
                             int* __restrict__ bcnt) {
    __shared__ int lds[256];
    __shared__ int hist[64];
    int t = threadIdx.x;
    int base = blockIdx.x * 1024 + t * 4;
    int dd[4], s = 0;
#pragma unroll
    for (int j = 0; j < 4; ++j) {
        dd[j] = (base + j < n) ? deg[base + j] : -1;
        if (dd[j] >= 0) s += dd[j];
    }
    lds[t] = s;
    if (t < 64) hist[t] = 0;
    __syncthreads();
#pragma unroll
    for (int j = 0; j < 4; ++j)
        if (dd[j] >= 0) atomicAdd(&hist[dd[j] < 63 ? dd[j] : 63], 1);
    for (int o = 128; o; o >>= 1) { if (t < o) lds[t] += lds[t + o]; __syncthreads(); }
    if (t == 0) bsum[blockIdx.x] = lds[0];
    if (t < 64 && hist[t]) atomicAdd(&bcnt[t], hist[t]);
}

// stage 2 (single block): scan block sums; ew-mean; zero stats; bucket scan -> bcursor
__global__ void scan_block(const int* __restrict__ bsum, int nb, int* __restrict__ boff,
                           int* __restrict__ row_start, int n, int total,
                           const float* __restrict__ partials, int nbp, int E,
                           float* __restrict__ stats,
                           const int* __restrict__ bcnt, int* __restrict__ bcursor) {
    __shared__ int lds[256];
    __shared__ float fred[256];
    int t = threadIdx.x;
    int v = (t < nb) ? bsum[t] : 0;
    lds[t] = v; __syncthreads();
    for (int o = 1; o < 256; o <<= 1) {
        int y = (t >= o) ? lds[t - o] : 0;
        __syncthreads();
        lds[t] += y;
        __syncthreads();
    }
    if (t < nb) boff[t] = lds[t] - v;   // exclusive
    if (t == 0) row_start[n] = total;
    stats[t] = 0.f; stats[256 + t] = 0.f;
    float fs = 0.f;
    for (int j = t; j < nbp; j += 256) fs += partials[j];
    fred[t] = fs; __syncthreads();
    for (int o = 128; o; o >>= 1) { if (t < o) fred[t] += fred[t + o]; __syncthreads(); }
    if (t == 0) stats[0] = fred[0] / (float)E;
    // exclusive scan of the 64 degree buckets -> bcursor
    __syncthreads();
    int bvv = (t < 64) ? bcnt[t] : 0;
    lds[t] = bvv; __syncthreads();
    for (int o = 1; o < 64; o <<= 1) {
        int y = (t >= o && t < 64) ? lds[t - o] : 0;
        __syncthreads();
        if (t < 64) lds[t] += y;
        __syncthreads();
    }
    if (t < 64) bcursor[t] = lds[t] - bvv;
}

// stage 3: per-block exclusive prefix; zero scatter cursors; counting-sort perm
__global__ void scan_final(const int* __restrict__ deg, int n, const int* __restrict__ boff,
                           int* __restrict__ row_start, int* __restrict__ cursor,
                           int* __restrict__ bcursor, int* __restrict__ perm) {
    __shared__ int lds[256];
    int t = threadIdx.x;
    int base = blockIdx.x * 1024 + t * 4;
    int d[4], loc[4], s = 0;
#pragma unroll
    for (int j = 0; j < 4; ++j) d[j] = (base + j < n) ? deg[base + j] : 0;
#pragma unroll
    for (int j = 0; j < 4; ++j) { loc[j] = s; s += d[j]; }
    lds[t] = s; __syncthreads();
    for (int o = 1; o < 256; o <<= 1) {
        int y = (t >= o) ? lds[t - o] : 0;
        __syncthreads();
        lds[t] += y;
        __syncthreads();
    }
    int texcl = lds[t] - s + boff[blockIdx.x];
#pragma unroll
    for (int j = 0; j < 4; ++j)
        if (base + j < n) { row_start[base + j] = texcl + loc[j]; cursor[base + j] = 0; }
    // ---- per-block counting sort into perm (lds reused: [0..63]=H, [64..127]=B, [128..191]=C)
    __syncthreads();
    if (t < 64) { lds[t] = 0; lds[128 + t] = 0; }
    __syncthreads();
    int bk[4];
#pragma unroll
    for (int j = 0; j < 4; ++j) {
        bk[j] = d[j] < 63 ? d[j] : 63;
        if (base + j < n) atomicAdd(&lds[bk[j]], 1);
    }
    __syncthreads();
    if (t < 64 && lds[t] > 0) lds[64 + t] = atomicAdd(&bcursor[t], lds[t]);
    __syncthreads();
#pragma unroll
    for (int j = 0; j < 4; ++j)
        if (base + j < n) {
            int pos = lds[64 + bk[j]] + atomicAdd(&lds[128 + bk[j]], 1);
            perm[pos] = base + j;
        }
}

// packed CSR entry: .x = src node, .y = edge weight bits (one 8B store/load)
__global__ void scatter_kernel(const int* __restrict__ ei, const float* __restrict__ ew,
                               const float* __restrict__ ew_mean, const int* __restrict__ row_start,
                               int* __restrict__ cursor, int2* __restrict__ csr,
                               int E, int N) {
    int e = blockIdx.x * blockDim.x + threadIdx.x;
    if (e >= E + N) return;
    int s, d; float w;
    if (e < E) { s = ei[e]; d = ei[E + e]; w = ew[e]; }
    else       { s = d = e - E;            w = ew_mean[0]; }
    int pos = row_start[d] + atomicAdd(&cursor[d], 1);
    csr[pos] = make_int2(s, __builtin_bit_cast(int, w));
}

// ---------------------------------------------------------------- persistent col-panel MFMA GEMM
// MODE 0: bf16 A passthrough. MODE 1: f32 A -> bf16 on the fly.
// MODE 2: bf16 A + fused BN+ELU (y = elu(Af*x + Bf)).
template <int MODE>
__global__ __launch_bounds__(512) void mfma_linear3(const void* __restrict__ Xv,
                                                    const ushort* __restrict__ WT,
                                                    const float* __restrict__ bnsums,
                                                    const float* __restrict__ gamma,
                                                    const float* __restrict__ beta,
                                                    const float* __restrict__ bl,
                                                    const float* __restrict__ br,
                                                    ushort* __restrict__ xl,
                                                    ushort* __restrict__ xr,
                                                    int n, int HALF) {
    constexpr int LW = (MODE == 1) ? 2 : 1;
    __shared__ ushort sB[128 * 128];
    __shared__ ushort sA[128 * 128];
    const int tid = threadIdx.x;
    const int c0 = blockIdx.x * 128;
    const int ntiles = (n + 127) >> 7;

    {
        const ushort* src = WT + (size_t)c0 * 128;
#pragma unroll
        for (int it = 0; it < 4; ++it) {
            int f = tid + it * 512;
            int row = f >> 4, ch = f & 15;
            const ushort* g = src + (size_t)row * 128 + ((ch ^ (row & 7)) << 3);
            ushort* lp = sB + (((size_t)it * 512 + (tid & ~63)) << 3);
            GLOAD_LDS16(g, lp);
        }
    }

    const int myc = (tid & 15) * 8;
    const int row0 = tid >> 4;
    const int swc = (tid & 15) ^ (row0 & 7);
    float Af[8], Bf[8];
    if constexpr (MODE == 2) {
        float invn = 1.f / (float)n;
#pragma unroll
        for (int j = 0; j < 8; ++j) {
            float mu = bnsums[myc + j] * invn;
            float var = bnsums[128 + myc + j] * invn - mu * mu;
            float rs = rsqrtf(var + 1e-5f);
            Af[j] = gamma[myc + j] * rs;
            Bf[j] = beta[myc + j] - mu * Af[j];
        }
    }

    uint4 rA[4][LW];
    auto loadA = [&](int rt) {
        int r0 = rt << 7;
#pragma unroll
        for (int it = 0; it < 4; ++it) {
            int gr = r0 + row0 + it * 32; gr = gr < n ? gr : n - 1;
            if constexpr (MODE == 1) {
                const float* src = (const float*)Xv + (size_t)gr * 128 + myc;
                rA[it][0] = *(const uint4*)src;
                rA[it][1] = *(const uint4*)(src + 4);
            } else {
                rA[it][0] = *(const uint4*)((const ushort*)Xv + (size_t)gr * 128 + myc);
            }
        }
    };
    auto writeA = [&]() {
#pragma unroll
        for (int it = 0; it < 4; ++it) {
            uint4 o;
            if constexpr (MODE == 0) {
                o = rA[it][0];
            } else if constexpr (MODE == 1) {
                float x[8] = {
                    __builtin_bit_cast(float, rA[it][0].x), __builtin_bit_cast(float, rA[it][0].y),
                    __builtin_bit_cast(float, rA[it][0].z), __builtin_bit_cast(float, rA[it][0].w),
                    __builtin_bit_cast(float, rA[it][1].x), __builtin_bit_cast(float, rA[it][1].y),
                    __builtin_bit_cast(float, rA[it][1].z), __builtin_bit_cast(float, rA[it][1].w)};
                ushort h[8];
#pragma unroll
                for (int j = 0; j < 8; ++j) h[j] = f2bf(x[j]);
                o.x = h[0] | ((uint32_t)h[1] << 16); o.y = h[2] | ((uint32_t)h[3] << 16);
                o.z = h[4] | ((uint32_t)h[5] << 16); o.w = h[6] | ((uint32_t)h[7] << 16);
            } else {
                float x[8]; dec8(rA[it][0], x);
                ushort h[8];
#pragma unroll
                for (int j = 0; j < 8; ++j) {
                    float v = fmaf(x[j], Af[j], Bf[j]);
                    v = v > 0.f ? v : __expf(v) - 1.f;   // ELU
                    h[j] = f2bf(v);
                }
                o.x = h[0] | ((uint32_t)h[1] << 16); o.y = h[2] | ((uint32_t)h[3] << 16);
                o.z = h[4] | ((uint32_t)h[5] << 16); o.w = h[6] | ((uint32_t)h[7] << 16);
            }
            *(uint4*)&sA[(row0 + it * 32) * 128 + swc * 8] = o;
        }
    };

    const int w = tid >> 6, l = tid & 63, lr = l & 15, lg = l >> 4;
    const bool left = c0 < HALF;
    const float* bias = left ? bl : br;
    ushort* dst = left ? xl : xr;
    const int cb = left ? c0 : c0 - HALF;
    float bv[8];
#pragma unroll
    for (int tn = 0; tn < 8; ++tn) bv[tn] = bias[cb + tn * 16 + lr];
    const int arow = w * 16 + lr;

    int rt = blockIdx.y;
    if (rt >= ntiles) return;
    loadA(rt);
    writeA();
    __syncthreads();

    while (true) {
        int nx = rt + gridDim.y;
        if (nx < ntiles) loadA(nx);

        f32x4 acc[8] = {};
#pragma unroll
        for (int kk = 0; kk < 4; ++kk) {
            int ach = (kk * 4 + lg) ^ (arow & 7);
            s16x8 a = *(const s16x8*)&sA[arow * 128 + (ach << 3)];
#pragma unroll
            for (int tn = 0; tn < 8; ++tn) {
                int brow = tn * 16 + lr;
                int bch = (kk * 4 + lg) ^ (brow & 7);
                s16x8 b = *(const s16x8*)&sB[brow * 128 + (bch << 3)];
                acc[tn] = __builtin_amdgcn_mfma_f32_16x16x32_bf16(a, b, acc[tn], 0, 0, 0);
            }
        }
        int rbase = (rt << 7) + w * 16 + lg * 4;
#pragma unroll
        for (int tn = 0; tn < 8; ++tn) {
            int colh = cb + tn * 16 + lr;
#pragma unroll
            for (int r = 0; r < 4; ++r) {
                int row = rbase + r;
                if (row < n) dst[(size_t)row * HALF + colh] = f2bf(acc[tn][r] + bv[tn]);
            }
        }
        if (nx >= ntiles) break;
        __syncthreads();
        writeA();
        __syncthreads();
        rt = nx;
    }
}

// ---------------------------------------------------------------- GATv2 aggregation (bf16 in/out)
// Nodes assigned via degree-sorted perm: co-scheduled nodes have matching
// degrees -> minimal exec-mask divergence in the pair loop. Depth-1 pair
// prefetch, UNCONDITIONAL clamped (r13 lesson). Defer-max softmax (exact).
template <int H, int C, int LPN>
__global__ __launch_bounds__(256, 6) void gat_agg(const ushort* __restrict__ xl,
                                                  const ushort* __restrict__ xr,
                                                  const int* __restrict__ row_start,
                                                  const int2* __restrict__ csr,
                                                  const int* __restrict__ perm,
                                                  const float* __restrict__ We,
                                                  const float* __restrict__ att,
                                                  const float* __restrict__ bias,
                                                  ushort* __restrict__ out, int n) {
    constexpr int HC = H * C;
    constexpr int VPL = HC / LPN;        // values per lane (8)
    constexpr int REDW = LPN / H;        // lanes per head
    constexpr int NPW = 64 / LPN;        // nodes per wave
    static_assert(VPL == 8, "");

    const int wid = threadIdx.x >> 6;
    const int lane = threadIdx.x & 63;
    const int sl = lane & (LPN - 1);
    const int sub = lane / LPN;
    const int slot = (blockIdx.x * 4 + wid) * NPW + sub;
    const bool valid = slot < n;
    const int vv = perm[valid ? slot : n - 1];   // degree-sorted node id

    const int base = sl * VPL;
    const int e0 = row_start[vv];
    const int e1 = row_start[vv + 1];
    const ushort* xlb = xl + base;

    auto LD = [&](int ee, uint4& g, float& w) {
        ee = ee < e1 - 1 ? ee : e1 - 1;  // clamp (dup row -> L1 hit)
        int2 sw = csr[ee];
        w = __builtin_bit_cast(float, sw.y);
        g = *(const uint4*)&xlb[(size_t)sw.x * HC];
    };

    // first edge row
    uint4 gF; float wF;
    LD(e0, gF, wF);
    // prefetch first pair (e0+1, e0+2), clamped
    uint4 gA, gB; float wA, wB;
    LD(e0 + 1, gA, wA);
    LD(e0 + 2, gB, wB);

    float xrv[8], wE[8], attv[8];
    dec8(*(const uint4*)&xr[(size_t)vv * HC + base], xrv);
#pragma unroll
    for (int j = 0; j < 8; j += 4) {
        float4 a = *(const float4*)&We[base + j];
        wE[j] = a.x; wE[j + 1] = a.y; wE[j + 2] = a.z; wE[j + 3] = a.w;
        float4 b = *(const float4*)&att[base + j];
        attv[j] = b.x; attv[j + 1] = b.y; attv[j + 2] = b.z; attv[j + 3] = b.w;
    }

    float m, den, acc[8];
    {   // first edge: m = p0, den = 1, acc = xf
        float xf[8];
        dec8(gF, xf);
        float t1 = 0.f, t2 = 0.f;
#pragma unroll
        for (int j = 0; j < 8; ++j) {
            float u = xf[j] + fmaf(wF, wE[j], xrv[j]);
            t1 = fmaf(u, attv[j], t1);
            t2 = fmaf(__builtin_fabsf(u), attv[j], t2);
        }
        float p = fmaf(0.6f, t1, 0.4f * t2);
#pragma unroll
        for (int o = REDW >> 1; o; o >>= 1) p += __shfl_xor(p, o, 64);
        m = p; den = 1.f;
#pragma unroll
        for (int j = 0; j < 8; ++j) acc[j] = xf[j];
    }

    int e = e0 + 1;
    while (e + 1 < e1) {                 // depth-1 pair loop
        uint4 g0 = gA, g1 = gB; float w0 = wA, w1 = wB;
        LD(e + 2, gA, wA);               // UNCONDITIONAL clamped prefetch:
        LD(e + 3, gB, wB);               // tail (if any) lands in gA = edge e+2
        float xf0[8], xf1[8];
        dec8(g0, xf0); dec8(g1, xf1);
        float t10 = 0.f, t20 = 0.f, t11 = 0.f, t21 = 0.f;
#pragma unroll
        for (int j = 0; j < 8; ++j) {
            float u0 = xf0[j] + fmaf(w0, wE[j], xrv[j]);
            float u1 = xf1[j] + fmaf(w1, wE[j], xrv[j]);
            t10 = fmaf(u0, attv[j], t10);
            t20 = fmaf(__builtin_fabsf(u0), attv[j], t20);
            t11 = fmaf(u1, attv[j], t11);
            t21 = fmaf(__builtin_fabsf(u1), attv[j], t21);
        }
        float p0 = fmaf(0.6f, t10, 0.4f * t20);
        float p1 = fmaf(0.6f, t11, 0.4f * t21);
#pragma unroll
        for (int o = REDW >> 1; o; o >>= 1) {
            p0 += __shfl_xor(p0, o, 64);
            p1 += __shfl_xor(p1, o, 64);
        }
        float pm = fmaxf(p0, p1);
        if (__builtin_expect(pm - m > 8.f, 0)) {   // rare: raise m, rescale history
            float r = __expf(m - pm);
            den *= r;
#pragma unroll
            for (int j = 0; j < 8; ++j) acc[j] *= r;
            m = pm;
        }
        float pe0 = __expf(p0 - m);
        float pe1 = __expf(p1 - m);
        den += pe0 + pe1;
#pragma unroll
        for (int j = 0; j < 8; ++j)
            acc[j] = fmaf(pe1, xf1[j], fmaf(pe0, xf0[j], acc[j]));
        e += 2;
    }
    if (e < e1) {                        // odd tail: edge e is in gA (prefetched clamped)
        float xf[8];
        dec8(gA, xf);
        float t1 = 0.f, t2 = 0.f;
#pragma unroll
        for (int j = 0; j < 8; ++j) {
            float u = xf[j] + fmaf(wA, wE[j], xrv[j]);
            t1 = fmaf(u, attv[j], t1);
            t2 = fmaf(__builtin_fabsf(u), attv[j], t2);
        }
        float p = fmaf(0.6f, t1, 0.4f * t2);
#pragma unroll
        for (int o = REDW >> 1; o; o >>= 1) p += __shfl_xor(p, o, 64);
        float dd = p - m;
        if (__builtin_expect(dd > 8.f, 0)) {
            float r = __expf(-dd);
            den = fmaf(den, r, 1.f);
#pragma unroll
            for (int j = 0; j < 8; ++j) acc[j] = fmaf(acc[j], r, xf[j]);
            m = p;
        } else {
            float pe = __expf(dd);
            den += pe;
#pragma unroll
            for (int j = 0; j < 8; ++j) acc[j] = fmaf(pe, xf[j], acc[j]);
        }
    }

    float inv = 1.f / den;
#pragma unroll
    for (int j = 0; j < 8; ++j) acc[j] *= inv;

    if constexpr (H > 1) {
#pragma unroll
        for (int o = REDW; o < LPN; o <<= 1)
#pragma unroll
            for (int j = 0; j < 8; ++j) acc[j] += __shfl_xor(acc[j], o, 64);
#pragma unroll
        for (int j = 0; j < 8; ++j) acc[j] *= (1.f / (float)H);
    }

    if (valid && sl < C / VPL) {
        float bv[8];
#pragma unroll
        for (int j = 0; j < 8; j += 4) {
            float4 b = *(const float4*)&bias[sl * VPL + j];
            bv[j] = b.x; bv[j + 1] = b.y; bv[j + 2] = b.z; bv[j + 3] = b.w;
        }
        uint4 o;
        o.x = (uint32_t)f2bf(acc[0] + bv[0]) | ((uint32_t)f2bf(acc[1] + bv[1]) << 16);
        o.y = (uint32_t)f2bf(acc[2] + bv[2]) | ((uint32_t)f2bf(acc[3] + bv[3]) << 16);
        o.z = (uint32_t)f2bf(acc[4] + bv[4]) | ((uint32_t)f2bf(acc[5] + bv[5]) << 16);
        o.w = (uint32_t)f2bf(acc[6] + bv[6]) | ((uint32_t)f2bf(acc[7] + bv[7]) << 16);
        *(uint4*)&out[(size_t)vv * C + sl * VPL] = o;
    }
}

// ---------------------------------------------------------------- batchnorm (bf16 in)
template <int C>
__global__ __launch_bounds__(256) void bn_stats_bf16(const ushort* __restrict__ x, int n,
                                                     float* __restrict__ sums) {
    constexpr int C2 = C / 2;
    constexpr int RPB = 256 / C2;
    __shared__ float red[256];
    int t = threadIdx.x;
    int c2 = t % C2, rs = t / C2;
    float s0 = 0.f, s1 = 0.f, q0 = 0.f, q1 = 0.f;
    for (int row = blockIdx.x * RPB + rs; row < n; row += gridDim.x * RPB) {
        uint32_t u = *(const uint32_t*)&x[(size_t)row * C + c2 * 2];
        float a = bflo(u), b = bfhi(u);
        s0 += a; q0 += a * a; s1 += b; q1 += b * b;
    }
    float vals[4] = {s0, s1, q0, q1};
    float outv[4];
#pragma unroll
    for (int k = 0; k < 4; ++k) {
        red[t] = vals[k]; __syncthreads();
        if (rs == 0) {
            float s = red[c2];
#pragma unroll
            for (int r = 1; r < RPB; ++r) s += red[c2 + r * C2];
            outv[k] = s;
        }
        __syncthreads();
    }
    if (rs == 0) {
        atomicAdd(&sums[c2 * 2],     outv[0]);
        atomicAdd(&sums[c2 * 2 + 1], outv[1]);
        atomicAdd(&sums[C + c2 * 2],     outv[2]);
        atomicAdd(&sums[C + c2 * 2 + 1], outv[3]);
    }
}

template <int C>
__global__ __launch_bounds__(256) void bn_apply_elu_f32(const ushort* __restrict__ x, int n,
                                                        const float* __restrict__ g,
                                                        const float* __restrict__ be,
                                                        const float* __restrict__ sums,
                                                        float* __restrict__ outf) {
    int total = n * C / 8;
    float invn = 1.f / (float)n;
    for (int i = blockIdx.x * blockDim.x + threadIdx.x; i < total; i += gridDim.x * blockDim.x) {
        uint4 u = ((const uint4*)x)[i];
        int c0 = (i * 8) & (C - 1);
        float r[8] = {bflo(u.x), bfhi(u.x), bflo(u.y), bfhi(u.y),
                      bflo(u.z), bfhi(u.z), bflo(u.w), bfhi(u.w)};
#pragma unroll
        for (int j = 0; j < 8; ++j) {
            int c = c0 + j;
            float mu = sums[c] * invn;
            float var = sums[C + c] * invn - mu * mu;
            float t = g[c] * (r[j] - mu) * rsqrtf(var + 1e-5f) + be[c];
            r[j] = t > 0.f ? t : expm1f(t);
        }
        ((float4*)outf)[i * 2]     = make_float4(r[0], r[1], r[2], r[3]);
        ((float4*)outf)[i * 2 + 1] = make_float4(r[4], r[5], r[6], r[7]);
    }
}

// ---------------------------------------------------------------- launch
extern "C" void kernel_launch(void* const* d_in, const int* in_sizes, int n_in,
                              void* d_out, int out_size, void* d_ws, size_t ws_size,
                              hipStream_t stream) {
    const float* emb = (const float*)d_in[0];
    const float* ew  = (const float*)d_in[1];
    const float* Wl0 = (const float*)d_in[2];
    const float* bl0 = (const float*)d_in[3];
    const float* Wr0 = (const float*)d_in[4];
    const float* br0 = (const float*)d_in[5];
    const float* We0 = (const float*)d_in[6];
    const float* att0 = (const float*)d_in[7];
    const float* b0  = (const float*)d_in[8];
    const float* g0  = (const float*)d_in[9];
    const float* be0 = (const float*)d_in[10];
    const float* Wl1 = (const float*)d_in[11];
    const float* bl1 = (const float*)d_in[12];
    const float* Wr1 = (const float*)d_in[13];
    const float* br1 = (const float*)d_in[14];
    const float* We1 = (const float*)d_in[15];
    const float* att1 = (const float*)d_in[16];
    const float* b1  = (const float*)d_in[17];
    const float* g1  = (const float*)d_in[18];
    const float* be1 = (const float*)d_in[19];
    const int* ei    = (const int*)d_in[20];

    const int N = in_sizes[0] / 128;
    const int E = in_sizes[1];
    const int Et = E + N;
    float* out = (float*)d_out;

    char* w = (char*)d_ws;
    size_t off = 0;
    auto alloc = [&](size_t bytes) {
        void* p = w + off;
        off = (off + bytes + 255) & ~(size_t)255;
        return p;
    };
    ushort* xlb    = (ushort*)alloc((size_t)N * 256 * 2);
    ushort* xrb    = (ushort*)alloc((size_t)N * 256 * 2);
    ushort* h0b16  = (ushort*)alloc((size_t)N * 128 * 2);   // gat0 out (pre-BN)
    ushort* out16  = (ushort*)alloc((size_t)N * 64 * 2);    // gat1 out (pre-BN)
    ushort* WT0    = (ushort*)alloc((size_t)256 * 128 * 2);
    ushort* WT1    = (ushort*)alloc((size_t)512 * 128 * 2);
    int*   deg     = (int*)alloc(((size_t)2 * N + 128) * 4); // [deg N][bcnt 64][cursor N][bcursor 64]
    int*   bcnt    = deg + N;
    int*   cursor  = deg + N + 64;
    int*   bcursor = deg + 2 * N + 64;
    int*   perm    = (int*)alloc((size_t)N * 4);
    int*   row_st  = (int*)alloc((size_t)(N + 1) * 4);
    int2*  csr     = (int2*)alloc((size_t)(Et + 8) * 8);    // packed (src, w)
    int*   bsum    = (int*)alloc(256 * 4);
    int*   boff    = (int*)alloc(256 * 4);
    float* partials= (float*)alloc(2048 * 4);
    float* stats   = (float*)alloc(512 * 4);                // ew_mean + bn0 + bn1
    float* ew_mean = stats;
    float* bn0     = stats + 64;
    float* bn1     = stats + 64 + 256;
    (void)ws_size; (void)n_in; (void)out_size;

    hipMemsetAsync(deg, 0, ((size_t)N + 64) * 4, stream);   // deg + bcnt

    const int NBE = (Et + 255) / 256;
    const int WTB = (128 * 256 + 128 * 512) / 256;          // 384
    degree_ew_wt<<<NBE + WTB, 256, 0, stream>>>(ei, ew, deg, partials, E, N, NBE,
                                                Wl0, Wr0, WT0, Wl1, Wr1, WT1);
    const int NB1 = (N + 1023) / 1024;
    scan_partial<<<NB1, 256, 0, stream>>>(deg, N, bsum, bcnt);
    scan_block<<<1, 256, 0, stream>>>(bsum, NB1, boff, row_st, N, Et, partials, NBE, E,
                                      stats, bcnt, bcursor);
    scan_final<<<NB1, 256, 0, stream>>>(deg, N, boff, row_st, cursor, bcursor, perm);
    scatter_kernel<<<NBE, 256, 0, stream>>>(ei, ew, ew_mean, row_st, cursor, csr, E, N);

    const int ntiles = (N + 127) / 128;
    const int GR = ntiles < 256 ? ntiles : 256;             // 2 blocks/CU

    // ---- layer 0 (emb read as f32 directly, converted in-register)
    mfma_linear3<1><<<dim3(2, GR), 512, 0, stream>>>(emb, WT0, nullptr, nullptr, nullptr,
                                                     bl0, br0, xlb, xrb, N, 128);
    gat_agg<1, 128, 16><<<(N + 15) / 16, 256, 0, stream>>>(xlb, xrb, row_st, csr, perm,
                                                           We0, att0, b0, h0b16, N);
    bn_stats_bf16<128><<<256, 256, 0, stream>>>(h0b16, N, bn0);

    // ---- layer 1 (BN+ELU of layer-0 fused into A-path of the GEMM)
    mfma_linear3<2><<<dim3(4, GR), 512, 0, stream>>>(h0b16, WT1, bn0, g0, be0,
                                                     bl1, br1, xlb, xrb, N, 256);
    gat_agg<4, 64, 32><<<(N + 7) / 8, 256, 0, stream>>>(xlb, xrb, row_st, csr, perm,
                                                        We1, att1, b1, out16, N);
    bn_stats_bf16<64><<<256, 256, 0, stream>>>(out16, N, bn1);
    bn_apply_elu_f32<64><<<1024, 256, 0, stream>>>(out16, N, g1, be1, bn1, out);
}

// Round 16
// 238.087 us; speedup vs baseline: 1.0202x; 1.0202x over previous
//
#include <hip/hip_runtime.h>
#include <cstdint>
#include <cstddef>
#include <type_traits>

using f32x4 = __attribute__((ext_vector_type(4))) float;
using s16x8 = __attribute__((ext_vector_type(8))) short;

__device__ __forceinline__ ushort f2bf(float x) {
    uint32_t u = __builtin_bit_cast(uint32_t, x);
    u += 0x7fffu + ((u >> 16) & 1u);          // round-to-nearest-even
    return (ushort)(u >> 16);
}
__device__ __forceinline__ float bflo(uint32_t u) { return __builtin_bit_cast(float, u << 16); }
__device__ __forceinline__ float bfhi(uint32_t u) { return __builtin_bit_cast(float, u & 0xffff0000u); }

__device__ __forceinline__ void dec8(uint4 g, float* x) {
    x[0] = bflo(g.x); x[1] = bfhi(g.x); x[2] = bflo(g.y); x[3] = bfhi(g.y);
    x[4] = bflo(g.z); x[5] = bfhi(g.z); x[6] = bflo(g.w); x[7] = bfhi(g.w);
}

#define GLOAD_LDS16(g, l)                                                                  \
    __builtin_amdgcn_global_load_lds((const __attribute__((address_space(1))) void*)(g),  \
                                     (__attribute__((address_space(3))) void*)(l), 16, 0, 0)

// ---------------------------------------------------------------- CSR build + WT prep (fused)
__global__ __launch_bounds__(256) void degree_ew_wt(const int* __restrict__ ei,
                                                    const float* __restrict__ ew,
                                                    int* __restrict__ deg,
                                                    float* __restrict__ partials,
                                                    int E, int N, int NBE,
                                                    const float* __restrict__ Wl0,
                                                    const float* __restrict__ Wr0,
                                                    ushort* __restrict__ WT0,
                                                    const float* __restrict__ Wl1,
                                                    const float* __restrict__ Wr1,
                                                    ushort* __restrict__ WT1) {
    __shared__ float red[256];
    int bid = blockIdx.x;
    int t = threadIdx.x;
    if (bid < NBE) {
        int e = bid * 256 + t;
        float s = (e < E) ? ew[e] : 0.f;
        red[t] = s; __syncthreads();
        for (int o = 128; o; o >>= 1) { if (t < o) red[t] += red[t + o]; __syncthreads(); }
        if (t == 0) partials[bid] = red[0];
        if (e < E + N) {
            int d = (e < E) ? ei[E + e] : (e - E);
            atomicAdd(&deg[d], 1);
        }
        return;
    }
    int j = (bid - NBE) * 256 + t;
    if (j < 128 * 256) {
        int k = j >> 8, c = j & 255;
        float v = (c < 128) ? Wl0[k * 128 + c] : Wr0[k * 128 + (c - 128)];
        WT0[(size_t)c * 128 + k] = f2bf(v);
        return;
    }
    j -= 128 * 256;
    if (j < 128 * 512) {
        int k = j >> 9, c = j & 511;
        float v = (c < 256) ? Wl1[k * 256 + c] : Wr1[k * 256 + (c - 256)];
        WT1[(size_t)c * 128 + k] = f2bf(v);
    }
}

// multi-block scan, stage 1: per-block (1024 elems) sums + degree-bucket histogram
__global__ void scan_partial(const int* __restrict__ deg, int n, int* __restrict__ bsum,
                             int* __restrict__ bcnt) {
    __shared__ int lds[256];
    __shared__ int hist[64];
    int t = threadIdx.x;
    int base = blockIdx.x * 1024 + t * 4;
    int dd[4], s = 0;
#pragma unroll
    for (int j = 0; j < 4; ++j) {
        dd[j] = (base + j < n) ? deg[base + j] : -1;
        if (dd[j] >= 0) s += dd[j];
    }
    lds[t] = s;
    if (t < 64) hist[t] = 0;
    __syncthreads();
#pragma unroll
    for (int j = 0; j < 4; ++j)
        if (dd[j] >= 0) atomicAdd(&hist[dd[j] < 63 ? dd[j] : 63], 1);
    for (int o = 128; o; o >>= 1) { if (t < o) lds[t] += lds[t + o]; __syncthreads(); }
    if (t == 0) bsum[blockIdx.x] = lds[0];
    if (t < 64 && hist[t]) atomicAdd(&bcnt[t], hist[t]);
}

// stage 2 (single block): scan block sums; ew-mean; zero stats;
// bucket suffix-scan -> bcursor (DESCENDING degree order = LPT scheduling)
__global__ void scan_block(const int* __restrict__ bsum, int nb, int* __restrict__ boff,
                           int* __restrict__ row_start, int n, int total,
                           const float* __restrict__ partials, int nbp, int E,
                           float* __restrict__ stats,
                           const int* __restrict__ bcnt, int* __restrict__ bcursor) {
    __shared__ int lds[256];
    __shared__ float fred[256];
    int t = threadIdx.x;
    int v = (t < nb) ? bsum[t] : 0;
    lds[t] = v; __syncthreads();
    for (int o = 1; o < 256; o <<= 1) {
        int y = (t >= o) ? lds[t - o] : 0;
        __syncthreads();
        lds[t] += y;
        __syncthreads();
    }
    if (t < nb) boff[t] = lds[t] - v;   // exclusive
    if (t == 0) row_start[n] = total;
    stats[t] = 0.f; stats[256 + t] = 0.f;
    float fs = 0.f;
    for (int j = t; j < nbp; j += 256) fs += partials[j];
    fred[t] = fs; __syncthreads();
    for (int o = 128; o; o >>= 1) { if (t < o) fred[t] += fred[t + o]; __syncthreads(); }
    if (t == 0) stats[0] = fred[0] / (float)E;
    // inclusive prefix over 64 buckets -> descending (suffix) exclusive offsets
    __syncthreads();
    int bvv = (t < 64) ? bcnt[t] : 0;
    lds[t] = bvv; __syncthreads();
    for (int o = 1; o < 64; o <<= 1) {
        int y = (t >= o && t < 64) ? lds[t - o] : 0;
        __syncthreads();
        if (t < 64) lds[t] += y;
        __syncthreads();
    }
    // bcursor[b] = count of nodes in buckets > b  (bucket 63 starts at 0)
    if (t < 64) bcursor[t] = lds[63] - lds[t];
}

// stage 3: per-block exclusive prefix; zero scatter cursors; counting-sort perm
__global__ void scan_final(const int* __restrict__ deg, int n, const int* __restrict__ boff,
                           int* __restrict__ row_start, int* __restrict__ cursor,
                           int* __restrict__ bcursor, int* __restrict__ perm) {
    __shared__ int lds[256];
    int t = threadIdx.x;
    int base = blockIdx.x * 1024 + t * 4;
    int d[4], loc[4], s = 0;
#pragma unroll
    for (int j = 0; j < 4; ++j) d[j] = (base + j < n) ? deg[base + j] : 0;
#pragma unroll
    for (int j = 0; j < 4; ++j) { loc[j] = s; s += d[j]; }
    lds[t] = s; __syncthreads();
    for (int o = 1; o < 256; o <<= 1) {
        int y = (t >= o) ? lds[t - o] : 0;
        __syncthreads();
        lds[t] += y;
        __syncthreads();
    }
    int texcl = lds[t] - s + boff[blockIdx.x];
#pragma unroll
    for (int j = 0; j < 4; ++j)
        if (base + j < n) { row_start[base + j] = texcl + loc[j]; cursor[base + j] = 0; }
    // ---- per-block counting sort into perm (lds reused: [0..63]=H, [64..127]=B, [128..191]=C)
    __syncthreads();
    if (t < 64) { lds[t] = 0; lds[128 + t] = 0; }
    __syncthreads();
    int bk[4];
#pragma unroll
    for (int j = 0; j < 4; ++j) {
        bk[j] = d[j] < 63 ? d[j] : 63;
        if (base + j < n) atomicAdd(&lds[bk[j]], 1);
    }
    __syncthreads();
    if (t < 64 && lds[t] > 0) lds[64 + t] = atomicAdd(&bcursor[t], lds[t]);
    __syncthreads();
#pragma unroll
    for (int j = 0; j < 4; ++j)
        if (base + j < n) {
            int pos = lds[64 + bk[j]] + atomicAdd(&lds[128 + bk[j]], 1);
            perm[pos] = base + j;
        }
}

// packed CSR entry: .x = src node, .y = edge weight bits (one 8B store/load)
__global__ void scatter_kernel(const int* __restrict__ ei, const float* __restrict__ ew,
                               const float* __restrict__ ew_mean, const int* __restrict__ row_start,
                               int* __restrict__ cursor, int2* __restrict__ csr,
                               int E, int N) {
    int e = blockIdx.x * blockDim.x + threadIdx.x;
    if (e >= E + N) return;
    int s, d; float w;
    if (e < E) { s = ei[e]; d = ei[E + e]; w = ew[e]; }
    else       { s = d = e - E;            w = ew_mean[0]; }
    int pos = row_start[d] + atomicAdd(&cursor[d], 1);
    csr[pos] = make_int2(s, __builtin_bit_cast(int, w));
}

// ---------------------------------------------------------------- persistent col-panel MFMA GEMM
// MODE 0: bf16 A passthrough. MODE 1: f32 A -> bf16 on the fly.
// MODE 2: bf16 A + fused BN+ELU (y = elu(Af*x + Bf)).
template <int MODE>
__global__ __launch_bounds__(512) void mfma_linear3(const void* __restrict__ Xv,
                                                    const ushort* __restrict__ WT,
                                                    const float* __restrict__ bnsums,
                                                    const float* __restrict__ gamma,
                                                    const float* __restrict__ beta,
                                                    const float* __restrict__ bl,
                                                    const float* __restrict__ br,
                                                    ushort* __restrict__ xl,
                                                    ushort* __restrict__ xr,
                                                    int n, int HALF) {
    constexpr int LW = (MODE == 1) ? 2 : 1;
    __shared__ ushort sB[128 * 128];
    __shared__ ushort sA[128 * 128];
    const int tid = threadIdx.x;
    const int c0 = blockIdx.x * 128;
    const int ntiles = (n + 127) >> 7;

    {
        const ushort* src = WT + (size_t)c0 * 128;
#pragma unroll
        for (int it = 0; it < 4; ++it) {
            int f = tid + it * 512;
            int row = f >> 4, ch = f & 15;
            const ushort* g = src + (size_t)row * 128 + ((ch ^ (row & 7)) << 3);
            ushort* lp = sB + (((size_t)it * 512 + (tid & ~63)) << 3);
            GLOAD_LDS16(g, lp);
        }
    }

    const int myc = (tid & 15) * 8;
    const int row0 = tid >> 4;
    const int swc = (tid & 15) ^ (row0 & 7);
    float Af[8], Bf[8];
    if constexpr (MODE == 2) {
        float invn = 1.f / (float)n;
#pragma unroll
        for (int j = 0; j < 8; ++j) {
            float mu = bnsums[myc + j] * invn;
            float var = bnsums[128 + myc + j] * invn - mu * mu;
            float rs = rsqrtf(var + 1e-5f);
            Af[j] = gamma[myc + j] * rs;
            Bf[j] = beta[myc + j] - mu * Af[j];
        }
    }

    uint4 rA[4][LW];
    auto loadA = [&](int rt) {
        int r0 = rt << 7;
#pragma unroll
        for (int it = 0; it < 4; ++it) {
            int gr = r0 + row0 + it * 32; gr = gr < n ? gr : n - 1;
            if constexpr (MODE == 1) {
                const float* src = (const float*)Xv + (size_t)gr * 128 + myc;
                rA[it][0] = *(const uint4*)src;
                rA[it][1] = *(const uint4*)(src + 4);
            } else {
                rA[it][0] = *(const uint4*)((const ushort*)Xv + (size_t)gr * 128 + myc);
            }
        }
    };
    auto writeA = [&]() {
#pragma unroll
        for (int it = 0; it < 4; ++it) {
            uint4 o;
            if constexpr (MODE == 0) {
                o = rA[it][0];
            } else if constexpr (MODE == 1) {
                float x[8] = {
                    __builtin_bit_cast(float, rA[it][0].x), __builtin_bit_cast(float, rA[it][0].y),
                    __builtin_bit_cast(float, rA[it][0].z), __builtin_bit_cast(float, rA[it][0].w),
                    __builtin_bit_cast(float, rA[it][1].x), __builtin_bit_cast(float, rA[it][1].y),
                    __builtin_bit_cast(float, rA[it][1].z), __builtin_bit_cast(float, rA[it][1].w)};
                ushort h[8];
#pragma unroll
                for (int j = 0; j < 8; ++j) h[j] = f2bf(x[j]);
                o.x = h[0] | ((uint32_t)h[1] << 16); o.y = h[2] | ((uint32_t)h[3] << 16);
                o.z = h[4] | ((uint32_t)h[5] << 16); o.w = h[6] | ((uint32_t)h[7] << 16);
            } else {
                float x[8]; dec8(rA[it][0], x);
                ushort h[8];
#pragma unroll
                for (int j = 0; j < 8; ++j) {
                    float v = fmaf(x[j], Af[j], Bf[j]);
                    v = v > 0.f ? v : __expf(v) - 1.f;   // ELU
                    h[j] = f2bf(v);
                }
                o.x = h[0] | ((uint32_t)h[1] << 16); o.y = h[2] | ((uint32_t)h[3] << 16);
                o.z = h[4] | ((uint32_t)h[5] << 16); o.w = h[6] | ((uint32_t)h[7] << 16);
            }
            *(uint4*)&sA[(row0 + it * 32) * 128 + swc * 8] = o;
        }
    };

    const int w = tid >> 6, l = tid & 63, lr = l & 15, lg = l >> 4;
    const bool left = c0 < HALF;
    const float* bias = left ? bl : br;
    ushort* dst = left ? xl : xr;
    const int cb = left ? c0 : c0 - HALF;
    float bv[8];
#pragma unroll
    for (int tn = 0; tn < 8; ++tn) bv[tn] = bias[cb + tn * 16 + lr];
    const int arow = w * 16 + lr;

    int rt = blockIdx.y;
    if (rt >= ntiles) return;
    loadA(rt);
    writeA();
    __syncthreads();

    while (true) {
        int nx = rt + gridDim.y;
        if (nx < ntiles) loadA(nx);

        f32x4 acc[8] = {};
#pragma unroll
        for (int kk = 0; kk < 4; ++kk) {
            int ach = (kk * 4 + lg) ^ (arow & 7);
            s16x8 a = *(const s16x8*)&sA[arow * 128 + (ach << 3)];
#pragma unroll
            for (int tn = 0; tn < 8; ++tn) {
                int brow = tn * 16 + lr;
                int bch = (kk * 4 + lg) ^ (brow & 7);
                s16x8 b = *(const s16x8*)&sB[brow * 128 + (bch << 3)];
                acc[tn] = __builtin_amdgcn_mfma_f32_16x16x32_bf16(a, b, acc[tn], 0, 0, 0);
            }
        }
        int rbase = (rt << 7) + w * 16 + lg * 4;
#pragma unroll
        for (int tn = 0; tn < 8; ++tn) {
            int colh = cb + tn * 16 + lr;
#pragma unroll
            for (int r = 0; r < 4; ++r) {
                int row = rbase + r;
                if (row < n) dst[(size_t)row * HALF + colh] = f2bf(acc[tn][r] + bv[tn]);
            }
        }
        if (nx >= ntiles) break;
        __syncthreads();
        writeA();
        __syncthreads();
        rt = nx;
    }
}

// ---------------------------------------------------------------- GATv2 aggregation (bf16 in/out)
// Degree-sorted perm in DESCENDING order (LPT: long blocks first, short tail).
// Depth-1 pair loop, register diet: decode buffers to xf BEFORE overwriting
// with the next UNCONDITIONAL clamped prefetch (r13 lesson). Defer-max softmax.
template <int H, int C, int LPN>
__global__ __launch_bounds__(256, 6) void gat_agg(const ushort* __restrict__ xl,
                                                  const ushort* __restrict__ xr,
                                                  const int* __restrict__ row_start,
                                                  const int2* __restrict__ csr,
                                                  const int* __restrict__ perm,
                                                  const float* __restrict__ We,
                                                  const float* __restrict__ att,
                                                  const float* __restrict__ bias,
                                                  ushort* __restrict__ out, int n) {
    constexpr int HC = H * C;
    constexpr int VPL = HC / LPN;        // values per lane (8)
    constexpr int REDW = LPN / H;        // lanes per head
    constexpr int NPW = 64 / LPN;        // nodes per wave
    static_assert(VPL == 8, "");

    const int wid = threadIdx.x >> 6;
    const int lane = threadIdx.x & 63;
    const int sl = lane & (LPN - 1);
    const int sub = lane / LPN;
    const int slot = (blockIdx.x * 4 + wid) * NPW + sub;
    const bool valid = slot < n;
    const int vv = perm[valid ? slot : n - 1];   // degree-sorted node id

    const int base = sl * VPL;
    const int e0 = row_start[vv];
    const int e1 = row_start[vv + 1];
    const ushort* xlb = xl + base;

    auto LD = [&](int ee, uint4& g, float& w) {
        ee = ee < e1 - 1 ? ee : e1 - 1;  // clamp (dup row -> L1 hit)
        int2 sw = csr[ee];
        w = __builtin_bit_cast(float, sw.y);
        g = *(const uint4*)&xlb[(size_t)sw.x * HC];
    };

    // first edge row
    uint4 gF; float wF;
    LD(e0, gF, wF);
    // prefetch first pair (e0+1, e0+2), clamped
    uint4 gA, gB; float wA, wB;
    LD(e0 + 1, gA, wA);
    LD(e0 + 2, gB, wB);

    float xrv[8], wE[8], attv[8];
    dec8(*(const uint4*)&xr[(size_t)vv * HC + base], xrv);
#pragma unroll
    for (int j = 0; j < 8; j += 4) {
        float4 a = *(const float4*)&We[base + j];
        wE[j] = a.x; wE[j + 1] = a.y; wE[j + 2] = a.z; wE[j + 3] = a.w;
        float4 b = *(const float4*)&att[base + j];
        attv[j] = b.x; attv[j + 1] = b.y; attv[j + 2] = b.z; attv[j + 3] = b.w;
    }

    float m, den, acc[8];
    {   // first edge: m = p0, den = 1, acc = xf
        float xf[8];
        dec8(gF, xf);
        float t1 = 0.f, t2 = 0.f;
#pragma unroll
        for (int j = 0; j < 8; ++j) {
            float u = xf[j] + fmaf(wF, wE[j], xrv[j]);
            t1 = fmaf(u, attv[j], t1);
            t2 = fmaf(__builtin_fabsf(u), attv[j], t2);
        }
        float p = fmaf(0.6f, t1, 0.4f * t2);
#pragma unroll
        for (int o = REDW >> 1; o; o >>= 1) p += __shfl_xor(p, o, 64);
        m = p; den = 1.f;
#pragma unroll
        for (int j = 0; j < 8; ++j) acc[j] = xf[j];
    }

    int e = e0 + 1;
    while (e + 1 < e1) {                 // depth-1 pair loop (register-diet form)
        float xf0[8], xf1[8];
        float w0 = wA, w1 = wB;
        dec8(gA, xf0); dec8(gB, xf1);    // consume buffers first...
        LD(e + 2, gA, wA);               // ...then overwrite with next pair
        LD(e + 3, gB, wB);               // (unconditional clamped; tail -> gA)
        float t10 = 0.f, t20 = 0.f, t11 = 0.f, t21 = 0.f;
#pragma unroll
        for (int j = 0; j < 8; ++j) {
            float u0 = xf0[j] + fmaf(w0, wE[j], xrv[j]);
            float u1 = xf1[j] + fmaf(w1, wE[j], xrv[j]);
            t10 = fmaf(u0, attv[j], t10);
            t20 = fmaf(__builtin_fabsf(u0), attv[j], t20);
            t11 = fmaf(u1, attv[j], t11);
            t21 = fmaf(__builtin_fabsf(u1), attv[j], t21);
        }
        float p0 = fmaf(0.6f, t10, 0.4f * t20);
        float p1 = fmaf(0.6f, t11, 0.4f * t21);
#pragma unroll
        for (int o = REDW >> 1; o; o >>= 1) {
            p0 += __shfl_xor(p0, o, 64);
            p1 += __shfl_xor(p1, o, 64);
        }
        float pm = fmaxf(p0, p1);
        if (__builtin_expect(pm - m > 8.f, 0)) {   // rare: raise m, rescale history
            float r = __expf(m - pm);
            den *= r;
#pragma unroll
            for (int j = 0; j < 8; ++j) acc[j] *= r;
            m = pm;
        }
        float pe0 = __expf(p0 - m);
        float pe1 = __expf(p1 - m);
        den += pe0 + pe1;
#pragma unroll
        for (int j = 0; j < 8; ++j)
            acc[j] = fmaf(pe1, xf1[j], fmaf(pe0, xf0[j], acc[j]));
        e += 2;
    }
    if (e < e1) {                        // odd tail: edge e is in gA (prefetched clamped)
        float xf[8];
        dec8(gA, xf);
        float t1 = 0.f, t2 = 0.f;
#pragma unroll
        for (int j = 0; j < 8; ++j) {
            float u = xf[j] + fmaf(wA, wE[j], xrv[j]);
            t1 = fmaf(u, attv[j], t1);
            t2 = fmaf(__builtin_fabsf(u), attv[j], t2);
        }
        float p = fmaf(0.6f, t1, 0.4f * t2);
#pragma unroll
        for (int o = REDW >> 1; o; o >>= 1) p += __shfl_xor(p, o, 64);
        float dd = p - m;
        if (__builtin_expect(dd > 8.f, 0)) {
            float r = __expf(-dd);
            den = fmaf(den, r, 1.f);
#pragma unroll
            for (int j = 0; j < 8; ++j) acc[j] = fmaf(acc[j], r, xf[j]);
            m = p;
        } else {
            float pe = __expf(dd);
            den += pe;
#pragma unroll
            for (int j = 0; j < 8; ++j) acc[j] = fmaf(pe, xf[j], acc[j]);
        }
    }

    float inv = 1.f / den;
#pragma unroll
    for (int j = 0; j < 8; ++j) acc[j] *= inv;

    if constexpr (H > 1) {
#pragma unroll
        for (int o = REDW; o < LPN; o <<= 1)
#pragma unroll
            for (int j = 0; j < 8; ++j) acc[j] += __shfl_xor(acc[j], o, 64);
#pragma unroll
        for (int j = 0; j < 8; ++j) acc[j] *= (1.f / (float)H);
    }

    if (valid && sl < C / VPL) {
        float bv[8];
#pragma unroll
        for (int j = 0; j < 8; j += 4) {
            float4 b = *(const float4*)&bias[sl * VPL + j];
            bv[j] = b.x; bv[j + 1] = b.y; bv[j + 2] = b.z; bv[j + 3] = b.w;
        }
        uint4 o;
        o.x = (uint32_t)f2bf(acc[0] + bv[0]) | ((uint32_t)f2bf(acc[1] + bv[1]) << 16);
        o.y = (uint32_t)f2bf(acc[2] + bv[2]) | ((uint32_t)f2bf(acc[3] + bv[3]) << 16);
        o.z = (uint32_t)f2bf(acc[4] + bv[4]) | ((uint32_t)f2bf(acc[5] + bv[5]) << 16);
        o.w = (uint32_t)f2bf(acc[6] + bv[6]) | ((uint32_t)f2bf(acc[7] + bv[7]) << 16);
        *(uint4*)&out[(size_t)vv * C + sl * VPL] = o;
    }
}

// ---------------------------------------------------------------- batchnorm (bf16 in)
template <int C>
__global__ __launch_bounds__(256) void bn_stats_bf16(const ushort* __restrict__ x, int n,
                                                     float* __restrict__ sums) {
    constexpr int C2 = C / 2;
    constexpr int RPB = 256 / C2;
    __shared__ float red[256];
    int t = threadIdx.x;
    int c2 = t % C2, rs = t / C2;
    float s0 = 0.f, s1 = 0.f, q0 = 0.f, q1 = 0.f;
    for (int row = blockIdx.x * RPB + rs; row < n; row += gridDim.x * RPB) {
        uint32_t u = *(const uint32_t*)&x[(size_t)row * C + c2 * 2];
        float a = bflo(u), b = bfhi(u);
        s0 += a; q0 += a * a; s1 += b; q1 += b * b;
    }
    float vals[4] = {s0, s1, q0, q1};
    float outv[4];
#pragma unroll
    for (int k = 0; k < 4; ++k) {
        red[t] = vals[k]; __syncthreads();
        if (rs == 0) {
            float s = red[c2];
#pragma unroll
            for (int r = 1; r < RPB; ++r) s += red[c2 + r * C2];
            outv[k] = s;
        }
        __syncthreads();
    }
    if (rs == 0) {
        atomicAdd(&sums[c2 * 2],     outv[0]);
        atomicAdd(&sums[c2 * 2 + 1], outv[1]);
        atomicAdd(&sums[C + c2 * 2],     outv[2]);
        atomicAdd(&sums[C + c2 * 2 + 1], outv[3]);
    }
}

template <int C>
__global__ __launch_bounds__(256) void bn_apply_elu_f32(const ushort* __restrict__ x, int n,
                                                        const float* __restrict__ g,
                                                        const float* __restrict__ be,
                                                        const float* __restrict__ sums,
                                                        float* __restrict__ outf) {
    int total = n * C / 8;
    float invn = 1.f / (float)n;
    for (int i = blockIdx.x * blockDim.x + threadIdx.x; i < total; i += gridDim.x * blockDim.x) {
        uint4 u = ((const uint4*)x)[i];
        int c0 = (i * 8) & (C - 1);
        float r[8] = {bflo(u.x), bfhi(u.x), bflo(u.y), bfhi(u.y),
                      bflo(u.z), bfhi(u.z), bflo(u.w), bfhi(u.w)};
#pragma unroll
        for (int j = 0; j < 8; ++j) {
            int c = c0 + j;
            float mu = sums[c] * invn;
            float var = sums[C + c] * invn - mu * mu;
            float t = g[c] * (r[j] - mu) * rsqrtf(var + 1e-5f) + be[c];
            r[j] = t > 0.f ? t : expm1f(t);
        }
        ((float4*)outf)[i * 2]     = make_float4(r[0], r[1], r[2], r[3]);
        ((float4*)outf)[i * 2 + 1] = make_float4(r[4], r[5], r[6], r[7]);
    }
}

// ---------------------------------------------------------------- launch
extern "C" void kernel_launch(void* const* d_in, const int* in_sizes, int n_in,
                              void* d_out, int out_size, void* d_ws, size_t ws_size,
                              hipStream_t stream) {
    const float* emb = (const float*)d_in[0];
    const float* ew  = (const float*)d_in[1];
    const float* Wl0 = (const float*)d_in[2];
    const float* bl0 = (const float*)d_in[3];
    const float* Wr0 = (const float*)d_in[4];
    const float* br0 = (const float*)d_in[5];
    const float* We0 = (const float*)d_in[6];
    const float* att0 = (const float*)d_in[7];
    const float* b0  = (const float*)d_in[8];
    const float* g0  = (const float*)d_in[9];
    const float* be0 = (const float*)d_in[10];
    const float* Wl1 = (const float*)d_in[11];
    const float* bl1 = (const float*)d_in[12];
    const float* Wr1 = (const float*)d_in[13];
    const float* br1 = (const float*)d_in[14];
    const float* We1 = (const float*)d_in[15];
    const float* att1 = (const float*)d_in[16];
    const float* b1  = (const float*)d_in[17];
    const float* g1  = (const float*)d_in[18];
    const float* be1 = (const float*)d_in[19];
    const int* ei    = (const int*)d_in[20];

    const int N = in_sizes[0] / 128;
    const int E = in_sizes[1];
    const int Et = E + N;
    float* out = (float*)d_out;

    char* w = (char*)d_ws;
    size_t off = 0;
    auto alloc = [&](size_t bytes) {
        void* p = w + off;
        off = (off + bytes + 255) & ~(size_t)255;
        return p;
    };
    ushort* xlb    = (ushort*)alloc((size_t)N * 256 * 2);
    ushort* xrb    = (ushort*)alloc((size_t)N * 256 * 2);
    ushort* h0b16  = (ushort*)alloc((size_t)N * 128 * 2);   // gat0 out (pre-BN)
    ushort* out16  = (ushort*)alloc((size_t)N * 64 * 2);    // gat1 out (pre-BN)
    ushort* WT0    = (ushort*)alloc((size_t)256 * 128 * 2);
    ushort* WT1    = (ushort*)alloc((size_t)512 * 128 * 2);
    int*   deg     = (int*)alloc(((size_t)2 * N + 128) * 4); // [deg N][bcnt 64][cursor N][bcursor 64]
    int*   bcnt    = deg + N;
    int*   cursor  = deg + N + 64;
    int*   bcursor = deg + 2 * N + 64;
    int*   perm    = (int*)alloc((size_t)N * 4);
    int*   row_st  = (int*)alloc((size_t)(N + 1) * 4);
    int2*  csr     = (int2*)alloc((size_t)(Et + 8) * 8);    // packed (src, w)
    int*   bsum    = (int*)alloc(256 * 4);
    int*   boff    = (int*)alloc(256 * 4);
    float* partials= (float*)alloc(2048 * 4);
    float* stats   = (float*)alloc(512 * 4);                // ew_mean + bn0 + bn1
    float* ew_mean = stats;
    float* bn0     = stats + 64;
    float* bn1     = stats + 64 + 256;
    (void)ws_size; (void)n_in; (void)out_size;

    hipMemsetAsync(deg, 0, ((size_t)N + 64) * 4, stream);   // deg + bcnt

    const int NBE = (Et + 255) / 256;
    const int WTB = (128 * 256 + 128 * 512) / 256;          // 384
    degree_ew_wt<<<NBE + WTB, 256, 0, stream>>>(ei, ew, deg, partials, E, N, NBE,
                                                Wl0, Wr0, WT0, Wl1, Wr1, WT1);
    const int NB1 = (N + 1023) / 1024;
    scan_partial<<<NB1, 256, 0, stream>>>(deg, N, bsum, bcnt);
    scan_block<<<1, 256, 0, stream>>>(bsum, NB1, boff, row_st, N, Et, partials, NBE, E,
                                      stats, bcnt, bcursor);
    scan_final<<<NB1, 256, 0, stream>>>(deg, N, boff, row_st, cursor, bcursor, perm);
    scatter_kernel<<<NBE, 256, 0, stream>>>(ei, ew, ew_mean, row_st, cursor, csr, E, N);

    const int ntiles = (N + 127) / 128;
    const int GR = ntiles < 256 ? ntiles : 256;             // 2 blocks/CU

    // ---- layer 0 (emb read as f32 directly, converted in-register)
    mfma_linear3<1><<<dim3(2, GR), 512, 0, stream>>>(emb, WT0, nullptr, nullptr, nullptr,
                                                     bl0, br0, xlb, xrb, N, 128);
    gat_agg<1, 128, 16><<<(N + 15) / 16, 256, 0, stream>>>(xlb, xrb, row_st, csr, perm,
                                                           We0, att0, b0, h0b16, N);
    bn_stats_bf16<128><<<256, 256, 0, stream>>>(h0b16, N, bn0);

    // ---- layer 1 (BN+ELU of layer-0 fused into A-path of the GEMM)
    mfma_linear3<2><<<dim3(4, GR), 512, 0, stream>>>(h0b16, WT1, bn0, g0, be0,
                                                     bl1, br1, xlb, xrb, N, 256);
    gat_agg<4, 64, 32><<<(N + 7) / 8, 256, 0, stream>>>(xlb, xrb, row_st, csr, perm,
                                                        We1, att1, b1, out16, N);
    bn_stats_bf16<64><<<256, 256, 0, stream>>>(out16, N, bn1);
    bn_apply_elu_f32<64><<<1024, 256, 0, stream>>>(out16, N, g1, be1, bn1, out);
}